// Round 11
// baseline (1975.630 us; speedup 1.0000x reference)
//
#include <hip/hip_runtime.h>

#define DI __device__ __forceinline__

typedef short bf16x8 __attribute__((ext_vector_type(8)));   // 8 bf16 (4 VGPRs)
typedef float f32x4 __attribute__((ext_vector_type(4)));    // 4 fp32 acc
typedef unsigned short u16;

static DI float bfu2f(unsigned short u) {
    return __uint_as_float(((unsigned)u) << 16);
}
static DI unsigned short f2bu(float f) {           // fp32 -> bf16 bits, RNE
    unsigned u = __float_as_uint(f);
    u += 0x7fffu + ((u >> 16) & 1u);
    return (unsigned short)(u >> 16);
}

// async global->LDS, 16B per lane; LDS base wave-uniform, global addr per-lane
static DI void gld16(const u16* g, u16* l) {
    __builtin_amdgcn_global_load_lds(
        (const __attribute__((address_space(1))) void*)g,
        (__attribute__((address_space(3))) void*)l, 16, 0, 0);
}

// XCD-aware block swizzle (grid.x*grid.y % 8 == 0 for all users -> bijective)
static DI void swz_block(int& bx, int& by) {
    const int gx = gridDim.x;
    const int n = gx * gridDim.y;
    const int ord = blockIdx.y * gx + blockIdx.x;
    const int cpx = n >> 3;
    const int s = (ord & 7) * cpx + (ord >> 3);
    bx = s % gx;
    by = s / gx;
}

__global__ void zinit(u16* z) { z[threadIdx.x] = 0; }   // 128B zero page

// =====================================================================
// Weight conversion kernels (once per layer)
// =====================================================================
__global__ __launch_bounds__(256) void cvt_1x1(
    const float* __restrict__ q, const float* __restrict__ k,
    const float* __restrict__ v, const float* __restrict__ o,
    u16* __restrict__ out)
{
    const int sel = blockIdx.y;
    const float* src = (sel == 0) ? q : (sel == 1) ? k : (sel == 2) ? v : o;
    const int i = blockIdx.x * 256 + threadIdx.x;       // float4 index
    const float4 w = ((const float4*)src)[i];
    ushort4 s;
    s.x = f2bu(w.x); s.y = f2bu(w.y); s.z = f2bu(w.z); s.w = f2bu(w.w);
    ((ushort4*)(out + (size_t)sel * 589824))[i] = s;
}

// [M][K][3] fp32 -> [3][M][K] bf16 tap planes.  grid = M*K/4/256 blocks
__global__ __launch_bounds__(256) void cvt_k3(
    const float* __restrict__ in, u16* __restrict__ out, int M, int K)
{
    const int i = blockIdx.x * 256 + threadIdx.x;       // (m, c4) index
    const int m = i / (K / 4);
    const int c4 = (i - m * (K / 4)) * 4;
    const float* ap = in + ((size_t)m * K + c4) * 3;
    const float4 w0 = *(const float4*)ap;
    const float4 w1 = *(const float4*)(ap + 4);
    const float4 w2 = *(const float4*)(ap + 8);
    ushort4 s0, s1, s2;
    s0.x = f2bu(w0.x); s0.y = f2bu(w0.w); s0.z = f2bu(w1.z); s0.w = f2bu(w2.y);
    s1.x = f2bu(w0.y); s1.y = f2bu(w1.x); s1.z = f2bu(w1.w); s1.w = f2bu(w2.z);
    s2.x = f2bu(w0.z); s2.y = f2bu(w1.y); s2.z = f2bu(w2.x); s2.w = f2bu(w2.w);
    const size_t PS = (size_t)M * K;
    const size_t off = (size_t)m * K + c4;
    *(ushort4*)(out + off) = s0;
    *(ushort4*)(out + PS + off) = s1;
    *(ushort4*)(out + 2 * PS + off) = s2;
}

// =====================================================================
// MFMA GEMM, async global_load_lds staging (R6 measured-best structure)
// + XOR granule swizzle.  Single-buffered (R9: DB at halved occupancy
// regresses).  C[g,m] = sum_{c,tap} W[tap][m][c] * B[g+tap-1, c] (+bias)
// LDS[row][gran] holds global granule gran ^ (row&7) (both-sides swizzle).
// 256 thr = 4 waves (2x2), wave tile (BM/2) x (BN/2).
// =====================================================================
template<int BM, int BN, int KS, bool MASK_IN, bool RELU, bool MASK_OUT>
static DI void gemm_dev(const u16* __restrict__ A, size_t PS,
                        const float* __restrict__ bias,
                        const u16* __restrict__ Bin,
                        u16* __restrict__ Cout,
                        const int* __restrict__ lens,
                        const u16* __restrict__ zpage,
                        int K, int ldB, int ldC, int m0, int n0)
{
    constexpr int HALO = (KS == 3) ? 1 : 0;
    constexpr int MI = BM / 32;
    constexpr int NI = BN / 32;
    constexpr int nACH = KS * BM / 8;      // 1KB chunks (8 rows x 128B)
    constexpr int nBCH = BN / 8;
    static_assert(nACH % 4 == 0 && nBCH % 4 == 0, "chunks per wave");

    __shared__ __align__(16) u16 As[KS * BM][64];
    __shared__ __align__(16) u16 Bs[BN + 2 * HALO][64];

    const int tid = threadIdx.x;
    const int batch = n0 >> 9;             // tile lies in one batch
    const int len0 = lens[batch];
    const int lane = tid & 63;
    const int wid = tid >> 6;
    const int wm = (wid >> 1) * (BM / 2);
    const int wn = (wid & 1) * (BN / 2);
    const int fr = lane & 15;
    const int fg = lane >> 4;
    const int l8 = lane >> 3;              // row within 8-row chunk
    const int lg = lane & 7;               // dest granule (16B unit)
    const int sga = lg ^ l8;               // A source granule
    const int sgb = lg ^ ((HALO + l8) & 7);// B source granule

    f32x4 acc[MI][NI];
#pragma unroll
    for (int i = 0; i < MI; ++i)
#pragma unroll
        for (int j = 0; j < NI; ++j) {
            f32x4 z = {0.f, 0.f, 0.f, 0.f};
            acc[i][j] = z;
        }

    for (int c0 = 0; c0 < K; c0 += 64) {
        // ---- A: async DMA, pre-swizzled source ----
#pragma unroll
        for (int c = 0; c < nACH / 4; ++c) {
            const int ch = c * 4 + wid;
            const int tap = (ch * 8) / BM;
            const int row0 = (ch * 8) & (BM - 1);
            const u16* g = A + (size_t)tap * PS
                             + (size_t)(m0 + row0 + l8) * K + c0 + sga * 8;
            gld16(g, &As[ch * 8][0]);
        }
        // ---- B main rows: async DMA; masked rows read the zero page ----
#pragma unroll
        for (int c = 0; c < nBCH / 4; ++c) {
            const int ch = c * 4 + wid;
            const int gr = n0 + ch * 8 + l8;
            bool v = true;
            if (MASK_IN) v = (gr & 511) < len0;
            const u16* g = v ? (Bin + (size_t)gr * ldB + c0 + sgb * 8)
                             : (zpage + sgb * 8);
            gld16(g, &Bs[HALO + ch * 8][0]);
        }
        // ---- B halo rows (KS==3): 16 lanes, sync, swizzled write ----
        if (KS == 3 && tid < 16) {
            const int hs = tid >> 3, j = tid & 7;
            const int rl = hs * (BN + 1);
            const int gr = n0 - 1 + hs * (BN + 1);
            bool v = ((unsigned)gr < 4096u) && ((gr >> 9) == batch);
            if (MASK_IN && v) v = (gr & 511) < len0;
            uint4 q = {0u, 0u, 0u, 0u};
            if (v) q = *(const uint4*)(Bin + (size_t)gr * ldB + c0 + j * 8);
            *(uint4*)&Bs[rl][(j ^ (rl & 7)) * 8] = q;
        }
        __syncthreads();                   // drains vmcnt (DMA) + lgkm
        // ---- compute: 2 x KS x MI x NI MFMAs, swizzled ds_read_b128 ----
#pragma unroll
        for (int kh = 0; kh < 2; ++kh) {
            const int kg = kh * 4;
#pragma unroll
            for (int tap = 0; tap < KS; ++tap) {
                bf16x8 af[MI], bgv[NI];
#pragma unroll
                for (int mi = 0; mi < MI; ++mi)
                    af[mi] = *(const bf16x8*)&As[tap * BM + wm + mi * 16 + fr]
                                               [((kg + fg) ^ (fr & 7)) * 8];
#pragma unroll
                for (int ni = 0; ni < NI; ++ni) {
                    const int lr = wn + ni * 16 + fr + tap;
                    bgv[ni] = *(const bf16x8*)&Bs[lr]
                                                [((kg + fg) ^ (lr & 7)) * 8];
                }
#pragma unroll
                for (int mi = 0; mi < MI; ++mi)
#pragma unroll
                    for (int ni = 0; ni < NI; ++ni)
                        acc[mi][ni] = __builtin_amdgcn_mfma_f32_16x16x32_bf16(
                            af[mi], bgv[ni], acc[mi][ni], 0, 0, 0);
            }
        }
        __syncthreads();
    }
    // ---- epilogue: D lane r -> m = base + (lane>>4)*4 + r ----
#pragma unroll
    for (int mi = 0; mi < MI; ++mi) {
        const int m = m0 + wm + mi * 16 + (lane >> 4) * 4;
        const float4 bi = *(const float4*)(bias + m);
#pragma unroll
        for (int ni = 0; ni < NI; ++ni) {
            const int g = n0 + wn + ni * 16 + fr;
            float r0 = acc[mi][ni][0] + bi.x;
            float r1 = acc[mi][ni][1] + bi.y;
            float r2 = acc[mi][ni][2] + bi.z;
            float r3 = acc[mi][ni][3] + bi.w;
            if (RELU) {
                r0 = fmaxf(r0, 0.f); r1 = fmaxf(r1, 0.f);
                r2 = fmaxf(r2, 0.f); r3 = fmaxf(r3, 0.f);
            }
            ushort4 s;
            s.x = f2bu(r0); s.y = f2bu(r1); s.z = f2bu(r2); s.w = f2bu(r3);
            if (MASK_OUT && ((g & 511) >= len0)) { s.x = 0; s.y = 0; s.z = 0; s.w = 0; }
            *(ushort4*)(Cout + (size_t)g * ldC + m) = s;
        }
    }
}

template<int BM, int BN, int KS, bool MASK_IN, bool RELU, bool MASK_OUT>
__global__ __launch_bounds__(256) void mfma_gemm(
    const u16* __restrict__ A, size_t PS, const float* __restrict__ bias,
    const u16* __restrict__ Bin, u16* __restrict__ Cout,
    const int* __restrict__ lens, const u16* __restrict__ zpage,
    int K, int ldB, int ldC)
{
    int bx, by;
    swz_block(bx, by);
    gemm_dev<BM, BN, KS, MASK_IN, RELU, MASK_OUT>(
        A, PS, bias, Bin, Cout, lens, zpage, K, ldB, ldC, by * BM, bx * BN);
}

// fused Q/K/V projection: by in [0,36): 12 row-tiles (BM=64) per matrix
__global__ __launch_bounds__(256) void mfma_qkv(
    const u16* __restrict__ W,
    const float* __restrict__ qb, const float* __restrict__ kb,
    const float* __restrict__ vb,
    const u16* __restrict__ Xb, u16* __restrict__ QKV,
    const int* __restrict__ lens, const u16* __restrict__ zpage)
{
    int bx, by;
    swz_block(bx, by);
    const int sel = by / 12;
    const int m0 = (by % 12) * 64;
    const u16* A = W + (size_t)sel * 589824;
    const float* bi = (sel == 0) ? qb : (sel == 1) ? kb : vb;
    gemm_dev<64, 128, 1, true, false, false>(
        A, 0, bi, Xb, QKV + sel * 768, lens, zpage, 768, 768, 2304, m0, bx * 128);
}

// =====================================================================
// V transpose per (b,h): QKV V-part [512 t][64 d] -> Vt[bh][64 d][512 t]
// =====================================================================
__global__ __launch_bounds__(256) void transp_v(
    const u16* __restrict__ QKV, u16* __restrict__ Vt)
{
    __shared__ u16 tile[64][65];
    const int tid = threadIdx.x;
    const int bh = blockIdx.y;
    const int b = bh / 12, h = bh - b * 12;
    const int t0 = blockIdx.x * 64;
    const u16* src = QKV + ((size_t)(b * 512 + t0)) * 2304 + 1536 + h * 64;
    const int rr = tid >> 2, c0 = (tid & 3) * 16;
#pragma unroll
    for (int j = 0; j < 4; ++j) {
        const ushort4 v = *(const ushort4*)(src + (size_t)rr * 2304 + c0 + j * 4);
        tile[rr][c0 + j * 4 + 0] = v.x;
        tile[rr][c0 + j * 4 + 1] = v.y;
        tile[rr][c0 + j * 4 + 2] = v.z;
        tile[rr][c0 + j * 4 + 3] = v.w;
    }
    __syncthreads();
    const int d = tid >> 2, tc = (tid & 3) * 16;
    u16* dst = Vt + (size_t)bh * 64 * 512 + (size_t)d * 512 + t0 + tc;
#pragma unroll
    for (int j = 0; j < 4; ++j) {
        ushort4 o;
        o.x = tile[tc + j * 4 + 0][d];
        o.y = tile[tc + j * 4 + 1][d];
        o.z = tile[tc + j * 4 + 2][d];
        o.w = tile[tc + j * 4 + 3][d];
        *(ushort4*)(dst + j * 4) = o;
    }
}

// =====================================================================
// MFMA attention: block = (32 q rows, one b*h). 512 thr = 8 waves.
// QBLK 16->32: halves block count, K/Vt traffic per row, and per-row
// fixed costs (Q-stage, RB serial loop, barriers). Same MFMA count,
// identical numerics. 73.9KB LDS -> 2 blocks/CU = 16 waves/CU (same
// wave-parallelism as the 16-row x 4-block config).
// QK: wave w = (row-half w&1) x (key-128-group w>>1).
// PV: wave w = (row-half w>>2) x (channel-16-group w&3).
// XCD-affinity: all 16 t-tiles of one bh on one XCD (neutral-measured,
// kept for L2 locality at 2 blocks/CU).
// =====================================================================
__global__ __launch_bounds__(512, 4) void attn_mfma(
    const u16* __restrict__ QKV, const u16* __restrict__ Vt,
    const float* __restrict__ relk, const float* __restrict__ relv,
    const int* __restrict__ lens, u16* __restrict__ Out)
{
    const int T = 512, H = 12;
    const int tid = threadIdx.x;
    // bijective decode: (8 xcd) x (12 bh/xcd) x (16 t-tiles of 32 rows)
    const int ord = blockIdx.y * 16 + blockIdx.x;
    const int xcd = ord & 7, rem = ord >> 3;
    const int bh = xcd * 12 + (rem % 12);
    const int t0 = (rem / 12) * 32;
    const int b = bh / H, h = bh - b * H;
    const int len = lens[b];

    __shared__ u16 Qs[32][72];          // 144B rows (16B-aligned)
    __shared__ float S[32][528];        // 2112B rows; P(hi|lo) aliased after softmax
    __shared__ float RB[32][12];
    __shared__ float Lsum[32];

    const int lane = tid & 63;
    const int w = tid >> 6;             // wave 0..7
    const int fr = lane & 15;
    const int fg = lane >> 4;

    // ---- stage Q (32 rows x 64 ch bf16): 512 thr x 4 ch ----
    {
        const int qr = tid >> 4, d4 = (tid & 15) * 4;
        const ushort4 q4 = *(const ushort4*)(
            QKV + ((size_t)(b * 512 + t0 + qr)) * 2304 + h * 64 + d4);
        *(ushort4*)&Qs[qr][d4] = q4;
    }
    __syncthreads();

    // ---- RB[r][o] = q[t0+r] . relk[o]  (unscaled, fp32 as before) ----
    if (tid < 288) {
        const int rr = tid / 9, o = tid - (tid / 9) * 9;
        float s = 0.f;
        for (int d = 0; d < 64; ++d) s += bfu2f(Qs[rr][d]) * relk[o * 64 + d];
        RB[rr][o] = s;
    }
    __syncthreads();

    // ---- phase 1: scores. wave w: rows 16*(w&1), keys [128*(w>>1), +128) ----
    {
        const int rg = (w & 1) * 16;
        const int kg0 = (w >> 1) * 128;
        bf16x8 qa0 = *(const bf16x8*)&Qs[rg + fr][fg * 8];
        bf16x8 qa1 = *(const bf16x8*)&Qs[rg + fr][32 + fg * 8];
        const u16* Kbase = QKV + ((size_t)(b * 512)) * 2304 + 768 + h * 64;
        f32x4 sa[8];
#pragma unroll
        for (int f = 0; f < 8; ++f) {
            const int s0 = kg0 + f * 16;
            const u16* kp = Kbase + (size_t)(s0 + fr) * 2304 + fg * 8;
            const bf16x8 kb0 = *(const bf16x8*)kp;
            const bf16x8 kb1 = *(const bf16x8*)(kp + 32);
            f32x4 z = {0.f, 0.f, 0.f, 0.f};
            z = __builtin_amdgcn_mfma_f32_16x16x32_bf16(qa0, kb0, z, 0, 0, 0);
            sa[f] = __builtin_amdgcn_mfma_f32_16x16x32_bf16(qa1, kb1, z, 0, 0, 0);
        }
#pragma unroll
        for (int f = 0; f < 8; ++f) {
            const int s_abs = kg0 + f * 16 + fr;
#pragma unroll
            for (int i = 0; i < 4; ++i) {
                const int r = rg + fg * 4 + i;
                const int t_abs = t0 + r;
                float v = sa[f][i];
                const int off = s_abs - t_abs;
                if (off >= -4 && off <= 4) v += RB[r][off + 4];
                v *= 0.125f;
                if (s_abs >= len || t_abs >= len) v = -1e4f;
                S[r][s_abs] = v;
            }
        }
    }
    __syncthreads();

    // ---- phase 2: softmax. 512 thr = 32 rows x 16 lanes; in-place P hi/lo ----
    {
        const int r = tid >> 4, lx = tid & 15;
        float sv[32];
        float mx = -3.0e38f;
#pragma unroll
        for (int j = 0; j < 32; ++j) {
            sv[j] = S[r][lx + 16 * j];
            mx = fmaxf(mx, sv[j]);
        }
#pragma unroll
        for (int m = 8; m >= 1; m >>= 1) mx = fmaxf(mx, __shfl_xor(mx, m));
        char* rowp = (char*)&S[0][0] + r * 2112;
        float sum = 0.f;
#pragma unroll
        for (int j = 0; j < 32; ++j) {
            const int c = lx + 16 * j;
            const float p = __expf(sv[j] - mx);
            sum += p;
            const u16 hi = f2bu(p);
            const u16 lo = f2bu(p - bfu2f(hi));
            *(u16*)(rowp + c * 2) = hi;
            *(u16*)(rowp + 1056 + c * 2) = lo;
        }
#pragma unroll
        for (int m = 8; m >= 1; m >>= 1) sum += __shfl_xor(sum, m);
        if (lx == 0) Lsum[r] = sum;
    }
    __syncthreads();

    // ---- phase 3: PV. wave w: rows 16*(w>>2), channels [16*(w&3), +16) ----
    const int rg = (w >> 2) * 16;
    const int cb = (w & 3) * 16;
    f32x4 oacc = {0.f, 0.f, 0.f, 0.f};
    {
        const u16* vtp = Vt + (size_t)bh * 64 * 512 + (size_t)(cb + fr) * 512;
        const char* prow = (const char*)&S[0][0] + (rg + fr) * 2112;
#pragma unroll 4
        for (int ks = 0; ks < 16; ++ks) {
            const int k0 = ks * 32;
            const bf16x8 pa_hi = *(const bf16x8*)(prow + (k0 + fg * 8) * 2);
            const bf16x8 pa_lo = *(const bf16x8*)(prow + 1056 + (k0 + fg * 8) * 2);
            const bf16x8 vb = *(const bf16x8*)(vtp + k0 + fg * 8);
            oacc = __builtin_amdgcn_mfma_f32_16x16x32_bf16(pa_hi, vb, oacc, 0, 0, 0);
            oacc = __builtin_amdgcn_mfma_f32_16x16x32_bf16(pa_lo, vb, oacc, 0, 0, 0);
        }
    }

    // ---- rel_v band + normalize + store ----
    {
        const int d = cb + fr;
        float rvv[9];
#pragma unroll
        for (int o = 0; o < 9; ++o) rvv[o] = relv[o * 64 + d];
        const char* Sbase = (const char*)&S[0][0];
#pragma unroll
        for (int i = 0; i < 4; ++i) {
            const int r = rg + fg * 4 + i;
            const int t_abs = t0 + r;
            float o = oacc[i];
            const char* rp = Sbase + r * 2112;
#pragma unroll
            for (int dd = 0; dd < 9; ++dd) {
                const int s = t_abs + dd - 4;
                if (s >= 0 && s < T) {
                    const float p = bfu2f(*(const u16*)(rp + s * 2))
                                  + bfu2f(*(const u16*)(rp + 1056 + s * 2));
                    o += p * rvv[dd];
                }
            }
            o *= 1.0f / Lsum[r];
            Out[((size_t)(b * 512 + t_abs)) * 768 + h * 64 + d] = f2bu(o);
        }
    }
}

// =====================================================================
// Fused residual + LayerNorm over channels; also emits bf16 copy (Xb)
// =====================================================================
__global__ __launch_bounds__(256) void ln_kernel(
    float* __restrict__ X, const u16* __restrict__ Y,
    const float* __restrict__ g, const float* __restrict__ bb,
    u16* __restrict__ Xb)
{
    const int row = blockIdx.x * 4 + (threadIdx.x >> 6);
    const int lane = threadIdx.x & 63;
    float* xp = X + (size_t)row * 768;
    const u16* yp = Y + (size_t)row * 768;
    u16* xbp = Xb + (size_t)row * 768;
    float v[12];
    float s1 = 0.f, s2 = 0.f;
#pragma unroll
    for (int j = 0; j < 3; ++j) {
        const int c = lane * 4 + j * 256;
        const float4 x4 = *(const float4*)(xp + c);
        const ushort4 y4 = *(const ushort4*)(yp + c);
        const float a0 = x4.x + bfu2f(y4.x);
        const float a1 = x4.y + bfu2f(y4.y);
        const float a2 = x4.z + bfu2f(y4.z);
        const float a3 = x4.w + bfu2f(y4.w);
        v[j * 4 + 0] = a0; v[j * 4 + 1] = a1; v[j * 4 + 2] = a2; v[j * 4 + 3] = a3;
        s1 += a0 + a1 + a2 + a3;
        s2 += a0 * a0 + a1 * a1 + a2 * a2 + a3 * a3;
    }
#pragma unroll
    for (int m = 32; m >= 1; m >>= 1) {
        s1 += __shfl_xor(s1, m);
        s2 += __shfl_xor(s2, m);
    }
    const float mean = s1 * (1.0f / 768.0f);
    const float rstd = rsqrtf(s2 * (1.0f / 768.0f) - mean * mean + 1e-5f);
#pragma unroll
    for (int j = 0; j < 3; ++j) {
        const int c = lane * 4 + j * 256;
        const float4 g4 = *(const float4*)(g + c);
        const float4 b4 = *(const float4*)(bb + c);
        float4 o;
        o.x = (v[j * 4 + 0] - mean) * rstd * g4.x + b4.x;
        o.y = (v[j * 4 + 1] - mean) * rstd * g4.y + b4.y;
        o.z = (v[j * 4 + 2] - mean) * rstd * g4.z + b4.z;
        o.w = (v[j * 4 + 3] - mean) * rstd * g4.w + b4.w;
        *(float4*)(xp + c) = o;
        ushort4 s;
        s.x = f2bu(o.x); s.y = f2bu(o.y); s.z = f2bu(o.z); s.w = f2bu(o.w);
        *(ushort4*)(xbp + c) = s;
    }
}

// ---------- layout transforms ----------
__global__ __launch_bounds__(256) void transpose_in(
    const float* __restrict__ in, float* __restrict__ X, u16* __restrict__ Xb)
{   // in [B][C][T] -> X [B][T][C] fp32 + bf16
    __shared__ float tile[32][33];
    const int b = blockIdx.z;
    const int t0 = blockIdx.x * 32, c0 = blockIdx.y * 32;
    const int lx = threadIdx.x & 31, ly = threadIdx.x >> 5;
    const float* ip = in + ((size_t)b * 768 + c0) * 512 + t0;
#pragma unroll
    for (int j = 0; j < 4; ++j)
        tile[ly + j * 8][lx] = ip[(size_t)(ly + j * 8) * 512 + lx];
    __syncthreads();
    float* xp = X + ((size_t)b * 512 + t0) * 768 + c0;
    u16* xbp = Xb + ((size_t)b * 512 + t0) * 768 + c0;
#pragma unroll
    for (int j = 0; j < 4; ++j) {
        const float val = tile[lx][ly + j * 8];
        xp[(size_t)(ly + j * 8) * 768 + lx] = val;
        xbp[(size_t)(ly + j * 8) * 768 + lx] = f2bu(val);
    }
}

__global__ __launch_bounds__(256) void finalize_kernel(
    const float* __restrict__ X, const int* __restrict__ lens,
    float* __restrict__ out)
{   // X [B][T][C] -> out [B][C][T], masked t < len
    __shared__ float tile[32][33];
    const int b = blockIdx.z;
    const int t0 = blockIdx.x * 32, c0 = blockIdx.y * 32;
    const int lx = threadIdx.x & 31, ly = threadIdx.x >> 5;
    const float* xp = X + ((size_t)b * 512 + t0) * 768 + c0;
#pragma unroll
    for (int j = 0; j < 4; ++j)
        tile[ly + j * 8][lx] = xp[(size_t)(ly + j * 8) * 768 + lx];
    __syncthreads();
    const int len = lens[b];
    float* op = out + ((size_t)b * 768 + c0) * 512 + t0;
    const bool on = (t0 + lx) < len;
#pragma unroll
    for (int j = 0; j < 4; ++j)
        op[(size_t)(ly + j * 8) * 512 + lx] = on ? tile[lx][ly + j * 8] : 0.0f;
}

// =====================================================================
extern "C" void kernel_launch(void* const* d_in, const int* in_sizes, int n_in,
                              void* d_out, int out_size, void* d_ws, size_t ws_size,
                              hipStream_t stream)
{
    (void)in_sizes; (void)n_in; (void)out_size; (void)ws_size;
    const int C = 768, FC = 3072, NL = 6;
    const size_t NROW = (size_t)8 * 512;   // flattened b*T rows

    const float* xin  = (const float*)d_in[0];
    const int*   lens = (const int*)d_in[1];
    const float* qw = (const float*)d_in[2];
    const float* qb = (const float*)d_in[3];
    const float* kw = (const float*)d_in[4];
    const float* kb = (const float*)d_in[5];
    const float* vw = (const float*)d_in[6];
    const float* vb = (const float*)d_in[7];
    const float* ow = (const float*)d_in[8];
    const float* ob = (const float*)d_in[9];
    const float* rk = (const float*)d_in[10];
    const float* rv = (const float*)d_in[11];
    const float* n1g = (const float*)d_in[12];
    const float* n1b = (const float*)d_in[13];
    const float* w1 = (const float*)d_in[14];
    const float* b1 = (const float*)d_in[15];
    const float* w2 = (const float*)d_in[16];
    const float* b2 = (const float*)d_in[17];
    const float* n2g = (const float*)d_in[18];
    const float* n2b = (const float*)d_in[19];

    // ---- workspace (~64.6 MB) ----
    // [ X fp32 ][ QKV bf16 [NROW][2304] ][ ATb ][ Yb ][ Xb ][ Wc 14.2MB ][ zp ]
    // H aliases QKV..ATb (3072 = 2304+768).  Vt aliases Yb.
    char* p0 = (char*)d_ws;
    float* X = (float*)p0;
    u16* QKV = (u16*)(p0 + NROW * 768 * 4);
    u16* ATb = QKV + NROW * 2304;
    u16* Yb  = ATb + NROW * 768;
    u16* Xb  = Yb + NROW * 768;
    u16* Wc  = Xb + NROW * 768;
    u16* zp  = Wc + (size_t)3 * FC * C;    // 128B zero page after largest Wc use
    u16* Hb  = QKV;   // alias
    u16* Vt  = Yb;    // alias

    zinit<<<dim3(1), 64, 0, stream>>>(zp);
    transpose_in<<<dim3(16, 24, 8), 256, 0, stream>>>(xin, X, Xb);

    for (int i = 0; i < NL; ++i) {
        cvt_1x1<<<dim3(576, 4), 256, 0, stream>>>(
            qw + (size_t)i * C * C, kw + (size_t)i * C * C,
            vw + (size_t)i * C * C, ow + (size_t)i * C * C, Wc);
        mfma_qkv<<<dim3(32, 36), 256, 0, stream>>>(
            Wc, qb + i * C, kb + i * C, vb + i * C, Xb, QKV, lens, zp);
        transp_v<<<dim3(8, 96), 256, 0, stream>>>(QKV, Vt);
        attn_mfma<<<dim3(16, 96), 512, 0, stream>>>(
            QKV, Vt, rk + (size_t)i * 9 * 64, rv + (size_t)i * 9 * 64, lens, ATb);
        mfma_gemm<64, 64, 1, false, false, false><<<dim3(64, 12), 256, 0, stream>>>(
            Wc + (size_t)3 * 589824, 0, ob + i * C, ATb, Yb, lens, zp, 768, 768, 768);
        ln_kernel<<<dim3(1024), 256, 0, stream>>>(X, Yb, n1g + i * C, n1b + i * C, Xb);
        cvt_k3<<<dim3(2304), 256, 0, stream>>>(
            w1 + (size_t)i * FC * C * 3, Wc, FC, C);
        mfma_gemm<64, 128, 3, true, true, true><<<dim3(32, 48), 256, 0, stream>>>(
            Wc, (size_t)FC * C, b1 + i * FC, Xb, Hb, lens, zp, 768, 768, 3072);
        cvt_k3<<<dim3(2304), 256, 0, stream>>>(
            w2 + (size_t)i * C * FC * 3, Wc, C, FC);
        mfma_gemm<64, 64, 3, false, false, true><<<dim3(64, 12), 256, 0, stream>>>(
            Wc, (size_t)C * FC, b2 + i * C, Hb, Yb, lens, zp, 3072, 3072, 768);
        ln_kernel<<<dim3(1024), 256, 0, stream>>>(X, Yb, n2g + i * C, n2b + i * C, Xb);
    }

    finalize_kernel<<<dim3(16, 24, 8), 256, 0, stream>>>(X, lens, (float*)d_out);
}

// Round 12
// 1922.759 us; speedup vs baseline: 1.0275x; 1.0275x over previous
//
#include <hip/hip_runtime.h>

#define DI __device__ __forceinline__

typedef short bf16x8 __attribute__((ext_vector_type(8)));   // 8 bf16 (4 VGPRs)
typedef float f32x4 __attribute__((ext_vector_type(4)));    // 4 fp32 acc
typedef unsigned short u16;

static DI float bfu2f(unsigned short u) {
    return __uint_as_float(((unsigned)u) << 16);
}
static DI unsigned short f2bu(float f) {           // fp32 -> bf16 bits, RNE
    unsigned u = __float_as_uint(f);
    u += 0x7fffu + ((u >> 16) & 1u);
    return (unsigned short)(u >> 16);
}

// async global->LDS, 16B per lane; LDS base wave-uniform, global addr per-lane
static DI void gld16(const u16* g, u16* l) {
    __builtin_amdgcn_global_load_lds(
        (const __attribute__((address_space(1))) void*)g,
        (__attribute__((address_space(3))) void*)l, 16, 0, 0);
}

// m-major block enumeration: consecutive dispatch ords (round-robin over
// XCDs) get consecutive by (m-tiles), so each XCD touches only
// gridDim.y/gcd(8,gridDim.y) distinct A-slices -> A stays L2-resident
// across that XCD's n-sweep (A re-read amplification served by L2 not L3).
static DI void swz_block(int& bx, int& by) {
    const int ord = blockIdx.y * gridDim.x + blockIdx.x;
    by = ord % gridDim.y;
    bx = ord / gridDim.y;
}

__global__ void zinit(u16* z) { z[threadIdx.x] = 0; }   // 128B zero page

// =====================================================================
// Weight conversion kernels (once per layer)
// =====================================================================
__global__ __launch_bounds__(256) void cvt_1x1(
    const float* __restrict__ q, const float* __restrict__ k,
    const float* __restrict__ v, const float* __restrict__ o,
    u16* __restrict__ out)
{
    const int sel = blockIdx.y;
    const float* src = (sel == 0) ? q : (sel == 1) ? k : (sel == 2) ? v : o;
    const int i = blockIdx.x * 256 + threadIdx.x;       // float4 index
    const float4 w = ((const float4*)src)[i];
    ushort4 s;
    s.x = f2bu(w.x); s.y = f2bu(w.y); s.z = f2bu(w.z); s.w = f2bu(w.w);
    ((ushort4*)(out + (size_t)sel * 589824))[i] = s;
}

// [M][K][3] fp32 -> [3][M][K] bf16 tap planes.  grid = M*K/4/256 blocks
__global__ __launch_bounds__(256) void cvt_k3(
    const float* __restrict__ in, u16* __restrict__ out, int M, int K)
{
    const int i = blockIdx.x * 256 + threadIdx.x;       // (m, c4) index
    const int m = i / (K / 4);
    const int c4 = (i - m * (K / 4)) * 4;
    const float* ap = in + ((size_t)m * K + c4) * 3;
    const float4 w0 = *(const float4*)ap;
    const float4 w1 = *(const float4*)(ap + 4);
    const float4 w2 = *(const float4*)(ap + 8);
    ushort4 s0, s1, s2;
    s0.x = f2bu(w0.x); s0.y = f2bu(w0.w); s0.z = f2bu(w1.z); s0.w = f2bu(w2.y);
    s1.x = f2bu(w0.y); s1.y = f2bu(w1.x); s1.z = f2bu(w1.w); s1.w = f2bu(w2.z);
    s2.x = f2bu(w0.z); s2.y = f2bu(w1.y); s2.z = f2bu(w2.x); s2.w = f2bu(w2.w);
    const size_t PS = (size_t)M * K;
    const size_t off = (size_t)m * K + c4;
    *(ushort4*)(out + off) = s0;
    *(ushort4*)(out + PS + off) = s1;
    *(ushort4*)(out + 2 * PS + off) = s2;
}

// =====================================================================
// MFMA GEMM, async global_load_lds staging (R6 measured-best structure)
// + XOR granule swizzle.  Single-buffered (R9: DB at halved occupancy
// regresses).  C[g,m] = sum_{c,tap} W[tap][m][c] * B[g+tap-1, c] (+bias)
// LDS[row][gran] holds global granule gran ^ (row&7) (both-sides swizzle).
// 256 thr = 4 waves (2x2), wave tile (BM/2) x (BN/2).
// =====================================================================
template<int BM, int BN, int KS, bool MASK_IN, bool RELU, bool MASK_OUT>
static DI void gemm_dev(const u16* __restrict__ A, size_t PS,
                        const float* __restrict__ bias,
                        const u16* __restrict__ Bin,
                        u16* __restrict__ Cout,
                        const int* __restrict__ lens,
                        const u16* __restrict__ zpage,
                        int K, int ldB, int ldC, int m0, int n0)
{
    constexpr int HALO = (KS == 3) ? 1 : 0;
    constexpr int MI = BM / 32;
    constexpr int NI = BN / 32;
    constexpr int nACH = KS * BM / 8;      // 1KB chunks (8 rows x 128B)
    constexpr int nBCH = BN / 8;
    static_assert(nACH % 4 == 0 && nBCH % 4 == 0, "chunks per wave");

    __shared__ __align__(16) u16 As[KS * BM][64];
    __shared__ __align__(16) u16 Bs[BN + 2 * HALO][64];

    const int tid = threadIdx.x;
    const int batch = n0 >> 9;             // tile lies in one batch
    const int len0 = lens[batch];
    const int lane = tid & 63;
    const int wid = tid >> 6;
    const int wm = (wid >> 1) * (BM / 2);
    const int wn = (wid & 1) * (BN / 2);
    const int fr = lane & 15;
    const int fg = lane >> 4;
    const int l8 = lane >> 3;              // row within 8-row chunk
    const int lg = lane & 7;               // dest granule (16B unit)
    const int sga = lg ^ l8;               // A source granule
    const int sgb = lg ^ ((HALO + l8) & 7);// B source granule

    f32x4 acc[MI][NI];
#pragma unroll
    for (int i = 0; i < MI; ++i)
#pragma unroll
        for (int j = 0; j < NI; ++j) {
            f32x4 z = {0.f, 0.f, 0.f, 0.f};
            acc[i][j] = z;
        }

    for (int c0 = 0; c0 < K; c0 += 64) {
        // ---- A: async DMA, pre-swizzled source ----
#pragma unroll
        for (int c = 0; c < nACH / 4; ++c) {
            const int ch = c * 4 + wid;
            const int tap = (ch * 8) / BM;
            const int row0 = (ch * 8) & (BM - 1);
            const u16* g = A + (size_t)tap * PS
                             + (size_t)(m0 + row0 + l8) * K + c0 + sga * 8;
            gld16(g, &As[ch * 8][0]);
        }
        // ---- B main rows: async DMA; masked rows read the zero page ----
#pragma unroll
        for (int c = 0; c < nBCH / 4; ++c) {
            const int ch = c * 4 + wid;
            const int gr = n0 + ch * 8 + l8;
            bool v = true;
            if (MASK_IN) v = (gr & 511) < len0;
            const u16* g = v ? (Bin + (size_t)gr * ldB + c0 + sgb * 8)
                             : (zpage + sgb * 8);
            gld16(g, &Bs[HALO + ch * 8][0]);
        }
        // ---- B halo rows (KS==3): 16 lanes, sync, swizzled write ----
        if (KS == 3 && tid < 16) {
            const int hs = tid >> 3, j = tid & 7;
            const int rl = hs * (BN + 1);
            const int gr = n0 - 1 + hs * (BN + 1);
            bool v = ((unsigned)gr < 4096u) && ((gr >> 9) == batch);
            if (MASK_IN && v) v = (gr & 511) < len0;
            uint4 q = {0u, 0u, 0u, 0u};
            if (v) q = *(const uint4*)(Bin + (size_t)gr * ldB + c0 + j * 8);
            *(uint4*)&Bs[rl][(j ^ (rl & 7)) * 8] = q;
        }
        __syncthreads();                   // drains vmcnt (DMA) + lgkm
        // ---- compute: 2 x KS x MI x NI MFMAs, swizzled ds_read_b128 ----
#pragma unroll
        for (int kh = 0; kh < 2; ++kh) {
            const int kg = kh * 4;
#pragma unroll
            for (int tap = 0; tap < KS; ++tap) {
                bf16x8 af[MI], bgv[NI];
#pragma unroll
                for (int mi = 0; mi < MI; ++mi)
                    af[mi] = *(const bf16x8*)&As[tap * BM + wm + mi * 16 + fr]
                                               [((kg + fg) ^ (fr & 7)) * 8];
#pragma unroll
                for (int ni = 0; ni < NI; ++ni) {
                    const int lr = wn + ni * 16 + fr + tap;
                    bgv[ni] = *(const bf16x8*)&Bs[lr]
                                                [((kg + fg) ^ (lr & 7)) * 8];
                }
#pragma unroll
                for (int mi = 0; mi < MI; ++mi)
#pragma unroll
                    for (int ni = 0; ni < NI; ++ni)
                        acc[mi][ni] = __builtin_amdgcn_mfma_f32_16x16x32_bf16(
                            af[mi], bgv[ni], acc[mi][ni], 0, 0, 0);
            }
        }
        __syncthreads();
    }
    // ---- epilogue: D lane r -> m = base + (lane>>4)*4 + r ----
#pragma unroll
    for (int mi = 0; mi < MI; ++mi) {
        const int m = m0 + wm + mi * 16 + (lane >> 4) * 4;
        const float4 bi = *(const float4*)(bias + m);
#pragma unroll
        for (int ni = 0; ni < NI; ++ni) {
            const int g = n0 + wn + ni * 16 + fr;
            float r0 = acc[mi][ni][0] + bi.x;
            float r1 = acc[mi][ni][1] + bi.y;
            float r2 = acc[mi][ni][2] + bi.z;
            float r3 = acc[mi][ni][3] + bi.w;
            if (RELU) {
                r0 = fmaxf(r0, 0.f); r1 = fmaxf(r1, 0.f);
                r2 = fmaxf(r2, 0.f); r3 = fmaxf(r3, 0.f);
            }
            ushort4 s;
            s.x = f2bu(r0); s.y = f2bu(r1); s.z = f2bu(r2); s.w = f2bu(r3);
            if (MASK_OUT && ((g & 511) >= len0)) { s.x = 0; s.y = 0; s.z = 0; s.w = 0; }
            *(ushort4*)(Cout + (size_t)g * ldC + m) = s;
        }
    }
}

template<int BM, int BN, int KS, bool MASK_IN, bool RELU, bool MASK_OUT>
__global__ __launch_bounds__(256) void mfma_gemm(
    const u16* __restrict__ A, size_t PS, const float* __restrict__ bias,
    const u16* __restrict__ Bin, u16* __restrict__ Cout,
    const int* __restrict__ lens, const u16* __restrict__ zpage,
    int K, int ldB, int ldC)
{
    int bx, by;
    swz_block(bx, by);
    gemm_dev<BM, BN, KS, MASK_IN, RELU, MASK_OUT>(
        A, PS, bias, Bin, Cout, lens, zpage, K, ldB, ldC, by * BM, bx * BN);
}

// fused Q/K/V projection: by in [0,36): 12 row-tiles (BM=64) per matrix
__global__ __launch_bounds__(256) void mfma_qkv(
    const u16* __restrict__ W,
    const float* __restrict__ qb, const float* __restrict__ kb,
    const float* __restrict__ vb,
    const u16* __restrict__ Xb, u16* __restrict__ QKV,
    const int* __restrict__ lens, const u16* __restrict__ zpage)
{
    int bx, by;
    swz_block(bx, by);
    const int sel = by / 12;
    const int m0 = (by % 12) * 64;
    const u16* A = W + (size_t)sel * 589824;
    const float* bi = (sel == 0) ? qb : (sel == 1) ? kb : vb;
    gemm_dev<64, 128, 1, true, false, false>(
        A, 0, bi, Xb, QKV + sel * 768, lens, zpage, 768, 768, 2304, m0, bx * 128);
}

// =====================================================================
// V transpose per (b,h): QKV V-part [512 t][64 d] -> Vt[bh][64 d][512 t]
// =====================================================================
__global__ __launch_bounds__(256) void transp_v(
    const u16* __restrict__ QKV, u16* __restrict__ Vt)
{
    __shared__ u16 tile[64][65];
    const int tid = threadIdx.x;
    const int bh = blockIdx.y;
    const int b = bh / 12, h = bh - b * 12;
    const int t0 = blockIdx.x * 64;
    const u16* src = QKV + ((size_t)(b * 512 + t0)) * 2304 + 1536 + h * 64;
    const int rr = tid >> 2, c0 = (tid & 3) * 16;
#pragma unroll
    for (int j = 0; j < 4; ++j) {
        const ushort4 v = *(const ushort4*)(src + (size_t)rr * 2304 + c0 + j * 4);
        tile[rr][c0 + j * 4 + 0] = v.x;
        tile[rr][c0 + j * 4 + 1] = v.y;
        tile[rr][c0 + j * 4 + 2] = v.z;
        tile[rr][c0 + j * 4 + 3] = v.w;
    }
    __syncthreads();
    const int d = tid >> 2, tc = (tid & 3) * 16;
    u16* dst = Vt + (size_t)bh * 64 * 512 + (size_t)d * 512 + t0 + tc;
#pragma unroll
    for (int j = 0; j < 4; ++j) {
        ushort4 o;
        o.x = tile[tc + j * 4 + 0][d];
        o.y = tile[tc + j * 4 + 1][d];
        o.z = tile[tc + j * 4 + 2][d];
        o.w = tile[tc + j * 4 + 3][d];
        *(ushort4*)(dst + j * 4) = o;
    }
}

// =====================================================================
// MFMA attention: block = (16 q rows, one b*h). 4 waves.  (R6 form:
// R11's QBLK=32/512-thr variant measured -43us; reverted.)
// =====================================================================
__global__ __launch_bounds__(256, 4) void attn_mfma(
    const u16* __restrict__ QKV, const u16* __restrict__ Vt,
    const float* __restrict__ relk, const float* __restrict__ relv,
    const int* __restrict__ lens, u16* __restrict__ Out)
{
    const int T = 512, H = 12;
    const int tid = threadIdx.x;
    const int t0 = blockIdx.x * 16;
    const int bh = blockIdx.y;
    const int b = bh / H, h = bh - b * H;
    const int len = lens[b];

    __shared__ u16 Qs[16][72];          // 144B rows (16B-aligned)
    __shared__ float S[16][528];        // 2112B rows; P(hi|lo) aliased after softmax
    __shared__ float RB[16][12];
    __shared__ float Lsum[16];

    const int lane = tid & 63;
    const int w = tid >> 6;
    const int fr = lane & 15;
    const int fg = lane >> 4;

    // ---- stage Q (16 rows x 64 ch bf16) ----
    {
        const int qr = tid >> 4, d4 = (tid & 15) * 4;
        const ushort4 q4 = *(const ushort4*)(
            QKV + ((size_t)(b * 512 + t0 + qr)) * 2304 + h * 64 + d4);
        *(ushort4*)&Qs[qr][d4] = q4;
    }
    __syncthreads();

    // ---- RB[r][o] = q[t0+r] . relk[o]  (unscaled) ----
    if (tid < 144) {
        const int rr = tid / 9, o = tid - (tid / 9) * 9;
        float s = 0.f;
        for (int d = 0; d < 64; ++d) s += bfu2f(Qs[rr][d]) * relk[o * 64 + d];
        RB[rr][o] = s;
    }
    __syncthreads();

    // ---- phase 1: scores via MFMA.  wave w: keys [128w, 128w+128) ----
    {
        bf16x8 qa0 = *(const bf16x8*)&Qs[fr][fg * 8];
        bf16x8 qa1 = *(const bf16x8*)&Qs[fr][32 + fg * 8];
        const u16* Kbase = QKV + ((size_t)(b * 512)) * 2304 + 768 + h * 64;
        f32x4 sa[8];
#pragma unroll
        for (int f = 0; f < 8; ++f) {
            const int s0 = w * 128 + f * 16;
            const u16* kp = Kbase + (size_t)(s0 + fr) * 2304 + fg * 8;
            const bf16x8 kb0 = *(const bf16x8*)kp;
            const bf16x8 kb1 = *(const bf16x8*)(kp + 32);
            f32x4 z = {0.f, 0.f, 0.f, 0.f};
            z = __builtin_amdgcn_mfma_f32_16x16x32_bf16(qa0, kb0, z, 0, 0, 0);
            sa[f] = __builtin_amdgcn_mfma_f32_16x16x32_bf16(qa1, kb1, z, 0, 0, 0);
        }
#pragma unroll
        for (int f = 0; f < 8; ++f) {
            const int s_abs = w * 128 + f * 16 + fr;
#pragma unroll
            for (int i = 0; i < 4; ++i) {
                const int r = fg * 4 + i;
                const int t_abs = t0 + r;
                float v = sa[f][i];
                const int off = s_abs - t_abs;
                if (off >= -4 && off <= 4) v += RB[r][off + 4];
                v *= 0.125f;
                if (s_abs >= len || t_abs >= len) v = -1e4f;
                S[r][s_abs] = v;
            }
        }
    }
    __syncthreads();

    // ---- phase 2: softmax (rows exclusive per wave; in-place P hi/lo) ----
    {
        const int r = tid >> 4, lx = tid & 15;
        float sv[32];
        float mx = -3.0e38f;
#pragma unroll
        for (int j = 0; j < 32; ++j) {
            sv[j] = S[r][lx + 16 * j];
            mx = fmaxf(mx, sv[j]);
        }
#pragma unroll
        for (int m = 8; m >= 1; m >>= 1) mx = fmaxf(mx, __shfl_xor(mx, m));
        char* rowp = (char*)&S[0][0] + r * 2112;
        float sum = 0.f;
#pragma unroll
        for (int j = 0; j < 32; ++j) {
            const int c = lx + 16 * j;
            const float p = __expf(sv[j] - mx);
            sum += p;
            const u16 hi = f2bu(p);
            const u16 lo = f2bu(p - bfu2f(hi));
            *(u16*)(rowp + c * 2) = hi;
            *(u16*)(rowp + 1056 + c * 2) = lo;
        }
#pragma unroll
        for (int m = 8; m >= 1; m >>= 1) sum += __shfl_xor(sum, m);
        if (lx == 0) Lsum[r] = sum;
    }
    __syncthreads();

    // ---- phase 3: PV via MFMA. wave w: channels [16w, 16w+16) ----
    f32x4 oacc = {0.f, 0.f, 0.f, 0.f};
    {
        const u16* vtp = Vt + (size_t)bh * 64 * 512 + (size_t)(w * 16 + fr) * 512;
        const char* prow = (const char*)&S[0][0] + fr * 2112;
#pragma unroll 4
        for (int ks = 0; ks < 16; ++ks) {
            const int k0 = ks * 32;
            const bf16x8 pa_hi = *(const bf16x8*)(prow + (k0 + fg * 8) * 2);
            const bf16x8 pa_lo = *(const bf16x8*)(prow + 1056 + (k0 + fg * 8) * 2);
            const bf16x8 vb = *(const bf16x8*)(vtp + k0 + fg * 8);
            oacc = __builtin_amdgcn_mfma_f32_16x16x32_bf16(pa_hi, vb, oacc, 0, 0, 0);
            oacc = __builtin_amdgcn_mfma_f32_16x16x32_bf16(pa_lo, vb, oacc, 0, 0, 0);
        }
    }

    // ---- rel_v band + normalize + store ----
    {
        const int d = w * 16 + fr;
        float rvv[9];
#pragma unroll
        for (int o = 0; o < 9; ++o) rvv[o] = relv[o * 64 + d];
        const char* Sbase = (const char*)&S[0][0];
#pragma unroll
        for (int i = 0; i < 4; ++i) {
            const int r = fg * 4 + i;
            const int t_abs = t0 + r;
            float o = oacc[i];
            const char* rp = Sbase + r * 2112;
#pragma unroll
            for (int dd = 0; dd < 9; ++dd) {
                const int s = t_abs + dd - 4;
                if (s >= 0 && s < T) {
                    const float p = bfu2f(*(const u16*)(rp + s * 2))
                                  + bfu2f(*(const u16*)(rp + 1056 + s * 2));
                    o += p * rvv[dd];
                }
            }
            o *= 1.0f / Lsum[r];
            Out[((size_t)(b * 512 + t_abs)) * 768 + h * 64 + d] = f2bu(o);
        }
    }
}

// =====================================================================
// Fused residual + LayerNorm over channels; also emits bf16 copy (Xb)
// =====================================================================
__global__ __launch_bounds__(256) void ln_kernel(
    float* __restrict__ X, const u16* __restrict__ Y,
    const float* __restrict__ g, const float* __restrict__ bb,
    u16* __restrict__ Xb)
{
    const int row = blockIdx.x * 4 + (threadIdx.x >> 6);
    const int lane = threadIdx.x & 63;
    float* xp = X + (size_t)row * 768;
    const u16* yp = Y + (size_t)row * 768;
    u16* xbp = Xb + (size_t)row * 768;
    float v[12];
    float s1 = 0.f, s2 = 0.f;
#pragma unroll
    for (int j = 0; j < 3; ++j) {
        const int c = lane * 4 + j * 256;
        const float4 x4 = *(const float4*)(xp + c);
        const ushort4 y4 = *(const ushort4*)(yp + c);
        const float a0 = x4.x + bfu2f(y4.x);
        const float a1 = x4.y + bfu2f(y4.y);
        const float a2 = x4.z + bfu2f(y4.z);
        const float a3 = x4.w + bfu2f(y4.w);
        v[j * 4 + 0] = a0; v[j * 4 + 1] = a1; v[j * 4 + 2] = a2; v[j * 4 + 3] = a3;
        s1 += a0 + a1 + a2 + a3;
        s2 += a0 * a0 + a1 * a1 + a2 * a2 + a3 * a3;
    }
#pragma unroll
    for (int m = 32; m >= 1; m >>= 1) {
        s1 += __shfl_xor(s1, m);
        s2 += __shfl_xor(s2, m);
    }
    const float mean = s1 * (1.0f / 768.0f);
    const float rstd = rsqrtf(s2 * (1.0f / 768.0f) - mean * mean + 1e-5f);
#pragma unroll
    for (int j = 0; j < 3; ++j) {
        const int c = lane * 4 + j * 256;
        const float4 g4 = *(const float4*)(g + c);
        const float4 b4 = *(const float4*)(bb + c);
        float4 o;
        o.x = (v[j * 4 + 0] - mean) * rstd * g4.x + b4.x;
        o.y = (v[j * 4 + 1] - mean) * rstd * g4.y + b4.y;
        o.z = (v[j * 4 + 2] - mean) * rstd * g4.z + b4.z;
        o.w = (v[j * 4 + 3] - mean) * rstd * g4.w + b4.w;
        *(float4*)(xp + c) = o;
        ushort4 s;
        s.x = f2bu(o.x); s.y = f2bu(o.y); s.z = f2bu(o.z); s.w = f2bu(o.w);
        *(ushort4*)(xbp + c) = s;
    }
}

// ---------- layout transforms ----------
__global__ __launch_bounds__(256) void transpose_in(
    const float* __restrict__ in, float* __restrict__ X, u16* __restrict__ Xb)
{   // in [B][C][T] -> X [B][T][C] fp32 + bf16
    __shared__ float tile[32][33];
    const int b = blockIdx.z;
    const int t0 = blockIdx.x * 32, c0 = blockIdx.y * 32;
    const int lx = threadIdx.x & 31, ly = threadIdx.x >> 5;
    const float* ip = in + ((size_t)b * 768 + c0) * 512 + t0;
#pragma unroll
    for (int j = 0; j < 4; ++j)
        tile[ly + j * 8][lx] = ip[(size_t)(ly + j * 8) * 512 + lx];
    __syncthreads();
    float* xp = X + ((size_t)b * 512 + t0) * 768 + c0;
    u16* xbp = Xb + ((size_t)b * 512 + t0) * 768 + c0;
#pragma unroll
    for (int j = 0; j < 4; ++j) {
        const float val = tile[lx][ly + j * 8];
        xp[(size_t)(ly + j * 8) * 768 + lx] = val;
        xbp[(size_t)(ly + j * 8) * 768 + lx] = f2bu(val);
    }
}

__global__ __launch_bounds__(256) void finalize_kernel(
    const float* __restrict__ X, const int* __restrict__ lens,
    float* __restrict__ out)
{   // X [B][T][C] -> out [B][C][T], masked t < len
    __shared__ float tile[32][33];
    const int b = blockIdx.z;
    const int t0 = blockIdx.x * 32, c0 = blockIdx.y * 32;
    const int lx = threadIdx.x & 31, ly = threadIdx.x >> 5;
    const float* xp = X + ((size_t)b * 512 + t0) * 768 + c0;
#pragma unroll
    for (int j = 0; j < 4; ++j)
        tile[ly + j * 8][lx] = xp[(size_t)(ly + j * 8) * 768 + lx];
    __syncthreads();
    const int len = lens[b];
    float* op = out + ((size_t)b * 768 + c0) * 512 + t0;
    const bool on = (t0 + lx) < len;
#pragma unroll
    for (int j = 0; j < 4; ++j)
        op[(size_t)(ly + j * 8) * 512 + lx] = on ? tile[lx][ly + j * 8] : 0.0f;
}

// =====================================================================
extern "C" void kernel_launch(void* const* d_in, const int* in_sizes, int n_in,
                              void* d_out, int out_size, void* d_ws, size_t ws_size,
                              hipStream_t stream)
{
    (void)in_sizes; (void)n_in; (void)out_size; (void)ws_size;
    const int C = 768, FC = 3072, NL = 6;
    const size_t NROW = (size_t)8 * 512;   // flattened b*T rows

    const float* xin  = (const float*)d_in[0];
    const int*   lens = (const int*)d_in[1];
    const float* qw = (const float*)d_in[2];
    const float* qb = (const float*)d_in[3];
    const float* kw = (const float*)d_in[4];
    const float* kb = (const float*)d_in[5];
    const float* vw = (const float*)d_in[6];
    const float* vb = (const float*)d_in[7];
    const float* ow = (const float*)d_in[8];
    const float* ob = (const float*)d_in[9];
    const float* rk = (const float*)d_in[10];
    const float* rv = (const float*)d_in[11];
    const float* n1g = (const float*)d_in[12];
    const float* n1b = (const float*)d_in[13];
    const float* w1 = (const float*)d_in[14];
    const float* b1 = (const float*)d_in[15];
    const float* w2 = (const float*)d_in[16];
    const float* b2 = (const float*)d_in[17];
    const float* n2g = (const float*)d_in[18];
    const float* n2b = (const float*)d_in[19];

    // ---- workspace (~64.6 MB) ----
    // [ X fp32 ][ QKV bf16 [NROW][2304] ][ ATb ][ Yb ][ Xb ][ Wc 14.2MB ][ zp ]
    // H aliases QKV..ATb (3072 = 2304+768).  Vt aliases Yb.
    char* p0 = (char*)d_ws;
    float* X = (float*)p0;
    u16* QKV = (u16*)(p0 + NROW * 768 * 4);
    u16* ATb = QKV + NROW * 2304;
    u16* Yb  = ATb + NROW * 768;
    u16* Xb  = Yb + NROW * 768;
    u16* Wc  = Xb + NROW * 768;
    u16* zp  = Wc + (size_t)3 * FC * C;    // 128B zero page after largest Wc use
    u16* Hb  = QKV;   // alias
    u16* Vt  = Yb;    // alias

    zinit<<<dim3(1), 64, 0, stream>>>(zp);
    transpose_in<<<dim3(16, 24, 8), 256, 0, stream>>>(xin, X, Xb);

    for (int i = 0; i < NL; ++i) {
        cvt_1x1<<<dim3(576, 4), 256, 0, stream>>>(
            qw + (size_t)i * C * C, kw + (size_t)i * C * C,
            vw + (size_t)i * C * C, ow + (size_t)i * C * C, Wc);
        mfma_qkv<<<dim3(32, 36), 256, 0, stream>>>(
            Wc, qb + i * C, kb + i * C, vb + i * C, Xb, QKV, lens, zp);
        transp_v<<<dim3(8, 96), 256, 0, stream>>>(QKV, Vt);
        attn_mfma<<<dim3(32, 96), 256, 0, stream>>>(
            QKV, Vt, rk + (size_t)i * 9 * 64, rv + (size_t)i * 9 * 64, lens, ATb);
        mfma_gemm<64, 64, 1, false, false, false><<<dim3(64, 12), 256, 0, stream>>>(
            Wc + (size_t)3 * 589824, 0, ob + i * C, ATb, Yb, lens, zp, 768, 768, 768);
        ln_kernel<<<dim3(1024), 256, 0, stream>>>(X, Yb, n1g + i * C, n1b + i * C, Xb);
        cvt_k3<<<dim3(2304), 256, 0, stream>>>(
            w1 + (size_t)i * FC * C * 3, Wc, FC, C);
        mfma_gemm<64, 128, 3, true, true, true><<<dim3(32, 48), 256, 0, stream>>>(
            Wc, (size_t)FC * C, b1 + i * FC, Xb, Hb, lens, zp, 768, 768, 3072);
        cvt_k3<<<dim3(2304), 256, 0, stream>>>(
            w2 + (size_t)i * C * FC * 3, Wc, C, FC);
        mfma_gemm<64, 64, 3, false, false, true><<<dim3(64, 12), 256, 0, stream>>>(
            Wc, (size_t)C * FC, b2 + i * C, Hb, Yb, lens, zp, 3072, 3072, 768);
        ln_kernel<<<dim3(1024), 256, 0, stream>>>(X, Yb, n2g + i * C, n2b + i * C, Xb);
    }

    finalize_kernel<<<dim3(16, 24, 8), 256, 0, stream>>>(X, lens, (float*)d_out);
}